// Round 5
// baseline (277.554 us; speedup 1.0000x reference)
//
#include <hip/hip_runtime.h>
#include <hip/hip_bf16.h>
#include <stdint.h>

typedef float v4f __attribute__((ext_vector_type(4)));
typedef short v8s __attribute__((ext_vector_type(8)));
typedef union { v8s v; unsigned u[4]; } v8u;

#define NB 40

__device__ __forceinline__ unsigned short f2b(float f) {
  __hip_bfloat16 h = __float2bfloat16(f);
  unsigned short u;
  __builtin_memcpy(&u, &h, 2);
  return u;
}
__device__ __forceinline__ unsigned pk2(float lo, float hi) {
  __hip_bfloat162 h = __float22bfloat162_rn(make_float2(lo, hi));
  unsigned u;
  __builtin_memcpy(&u, &h, 4);
  return u;
}
__device__ __forceinline__ float b2f16(unsigned short h) {
  return __uint_as_float(((unsigned)h) << 16);
}
__device__ __forceinline__ float blo(unsigned u) { return __uint_as_float(u << 16); }
__device__ __forceinline__ float bhi(unsigned u) { return __uint_as_float(u & 0xFFFF0000u); }

// ws layout (bytes):
//  A1pk   @ 0        : 12288     (2t x 3nt x 2ks A^T A-frags, zero n>=40 / m>=40)
//  W2pk   @ 12288    : 32768     (2t x 4ks x 4dt B-frags of gnn_w)
//  Gpk    @ 45056    : 245760    (80kt x 3jt A-frags of gate_w^T, K-order fl'=d*40+n)
//  s1     @ 290816   : 20480     s for f<64, [t][n][d] f32
//  sNT    @ 311296   : 20480+128 s for f>=64, [t][d][n] f32 (+pad)
//  bias2T @ 331904   : 20480     gnn_b + all-BN-offset fold, [t][d][n] f32
//  hLg    @ 352512   : 83886080  h' bf16 [b][t][d*40+n]  (d-major)

// prep: params only. block 0: adjacency -> LN -> softmax -> A1pk (wave-parallel).
// blocks 1..63: everything else.  Gpk uses K-order fl' = d*40+n to match hLg.
__global__ __launch_bounds__(256) void prep(
    const float* __restrict__ masker,
    const float* __restrict__ ln_gamma, const float* __restrict__ ln_beta,
    const float* __restrict__ gnn_w, const float* __restrict__ gnn_b,
    const float* __restrict__ bn_gamma, const float* __restrict__ bn_beta,
    const float* __restrict__ bn_mean, const float* __restrict__ bn_var,
    const float* __restrict__ gate_w,
    unsigned short* __restrict__ A1pk, unsigned short* __restrict__ W2pk,
    unsigned short* __restrict__ Gpk, float* __restrict__ s1,
    float* __restrict__ sNT, float* __restrict__ bias2T)
{
  const int tid = threadIdx.x;
  if (blockIdx.x == 0) {
    __shared__ float AtL[2 * NB * NB];
    const int w = tid >> 6, lane = tid & 63;
    #pragma unroll 1
    for (int it = 0; it < 20; ++it) {
      const int c = it * 4 + w;        // 0..79
      const int t = c / NB, n = c % NB;
      const int m = lane;              // valid < 40
      float adj = 0.f;
      if (m < NB) {
        float p = masker[((t*3+0)*NB+m)*NB+n]
                * masker[((t*3+1)*NB+m)*NB+n]
                * masker[((t*3+2)*NB+m)*NB+n];
        adj = p > 0.f ? p : 0.f;
      }
      float s = adj;
      #pragma unroll
      for (int d = 1; d < 64; d <<= 1) s += __shfl_xor(s, d);
      const float mu = s * (1.f/NB);
      const float dv = (m < NB) ? adj - mu : 0.f;
      float v2 = dv * dv;
      #pragma unroll
      for (int d = 1; d < 64; d <<= 1) v2 += __shfl_xor(v2, d);
      const float inv = rsqrtf(v2 * (1.f/NB) + 1e-5f);
      float val = -3.0e38f;
      if (m < NB) {
        float lnv = dv * inv * ln_gamma[m] + ln_beta[m];
        val = lnv + (adj != 0.f ? 0.f : -1e9f) + (m == n ? 1.f : 0.f);
      }
      float mx = val;
      #pragma unroll
      for (int d = 1; d < 64; d <<= 1) mx = fmaxf(mx, __shfl_xor(mx, d));
      const float e = (m < NB) ? __expf(val - mx) : 0.f;
      float es = e;
      #pragma unroll
      for (int d = 1; d < 64; d <<= 1) es += __shfl_xor(es, d);
      if (m < NB)
        AtL[(t*NB+n)*NB + m] = (adj != 0.f) ? e / es : 0.f;
    }
    __syncthreads();
    for (int e = tid; e < 6144; e += 256) {
      int frag = e >> 9, rem = e & 511, lane2 = rem >> 3, jj = rem & 7;
      int t = frag / 6, r2 = frag % 6, nt = r2 >> 1, ks = r2 & 1;
      int n = nt*16 + (lane2 & 15);
      int m = ks*32 + (lane2 >> 4)*8 + jj;
      A1pk[e] = f2b((n < NB && m < NB) ? AtL[(t*NB+n)*NB+m] : 0.f);
    }
  } else {
    const int gid = (blockIdx.x - 1) * 256 + tid, gsz = 63 * 256;
    for (int e = gid; e < 16384; e += gsz) {
      int frag = e >> 9, rem = e & 511, lane = rem >> 3, jj = rem & 7;
      int t = frag >> 4, ks = (frag >> 2) & 3, dt = frag & 3;
      int f = ks*32 + (lane >> 4)*8 + jj, d = dt*16 + (lane & 15);
      W2pk[e] = f2b(gnn_w[t*8192 + f*64 + d]);
    }
    // Gpk: K-dim reordered fl' = d*40+n (matches d-major hLg)
    for (int e = gid; e < 122880; e += gsz) {
      int frag = e >> 9, rem = e & 511, lane = rem >> 3, jj = rem & 7;
      int kt = frag / 3, jt = frag % 3;
      int flp = kt*32 + (lane >> 4)*8 + jj;
      int dd = flp / 40, nn = flp - dd*40;
      int j = jt*16 + (lane & 15);
      Gpk[e] = f2b(j < NB ? gate_w[(nn*64 + dd)*NB + j] : 0.f);
    }
    for (int e = gid; e < 5120; e += gsz) {
      int t = e / 2560, n = (e % 2560) / 64, d = e & 63;
      int F = (t*NB + n)*128 + d;
      s1[e] = bn_gamma[F] * rsqrtf(bn_var[F] + 1e-5f);
    }
    for (int e = gid; e < 5120; e += gsz) {
      int t = e / 2560, d = (e % 2560) / 40, n = e % 40;
      int F = (t*NB + n)*128 + 64 + d;
      sNT[e] = bn_gamma[F] * rsqrtf(bn_var[F] + 1e-5f);
    }
    for (int e4 = gid; e4 < 20480; e4 += gsz) {
      int e = e4 >> 2, part = e4 & 3;
      int t = e / 2560, d = (e % 2560) / 40, n = e % 40;
      float acc = (part == 0) ? gnn_b[(t*NB + n)*64 + d] : 0.f;
      int Fb = (t*NB + n)*128;
      int f0 = part * 32;
      for (int f = f0; f < f0 + 32; ++f) {
        float s = bn_gamma[Fb+f] * rsqrtf(bn_var[Fb+f] + 1e-5f);
        float o = bn_beta[Fb+f] - bn_mean[Fb+f] * s;
        acc += o * gnn_w[t*8192 + f*64 + d];
      }
      acc += __shfl_xor(acc, 1);
      acc += __shfl_xor(acc, 2);
      if (part == 0) bias2T[e] = acc;
    }
  }
}

// kernelA: barrier-free, wave-local, LDS-minimal. Wave w owns batch b0+w.
// U (=s1.*x) GEMM2-A-frags and x^T GEMM1-B-frags are built DIRECTLY from
// global in registers (frag-layout loads); only V (GEMM1 out -> GEMM2 in
// transpose) round-trips LDS. LDS 24192 B -> 6 blocks/CU (24 waves/CU).
__global__ __launch_bounds__(256) void kernelA(
    const float* __restrict__ x,
    const unsigned short* __restrict__ A1pk, const unsigned short* __restrict__ W2pk,
    const float* __restrict__ s1, const float* __restrict__ sNT,
    const float* __restrict__ bias2T, unsigned short* __restrict__ hLg)
{
  __shared__ __align__(16) unsigned short sh[4*2880 + 576];  // 24192 B

  const int tid = threadIdx.x;
  const int lane = tid & 63;
  const int w = tid >> 6;
  const int l15 = lane & 15, q = lane >> 4;
  const int b = blockIdx.x * 4 + w;

  unsigned short* Vw = sh + w * 2880;    // V [40][72] bf16 (A-frag reads overrun
                                         // rows 40..47 into next region / tail pad;
                                         // those outputs are discarded)
  const float* xb = x + (size_t)b * 2560;

  // ---- GEMM1 B-frags straight from global: b1[dt][ks], col d, k-dim m ----
  v8s b1[4][2];
  #pragma unroll
  for (int dt = 0; dt < 4; ++dt) {
    const int d = dt*16 + l15;
    v8u u0;
    #pragma unroll
    for (int j2 = 0; j2 < 4; ++j2)
      u0.u[j2] = pk2(xb[(q*8 + 2*j2    )*64 + d],
                     xb[(q*8 + 2*j2 + 1)*64 + d]);
    b1[dt][0] = u0.v;
    v8s bk1 = {0,0,0,0,0,0,0,0};
    if (q == 0) {                       // m = 32..39 valid; m>=40 zero (A side 0 too)
      v8u u1;
      #pragma unroll
      for (int j2 = 0; j2 < 4; ++j2)
        u1.u[j2] = pk2(xb[(32 + 2*j2    )*64 + d],
                       xb[(32 + 2*j2 + 1)*64 + d]);
      bk1 = u1.v;
    }
    b1[dt][1] = bk1;
  }

  #pragma unroll 1
  for (int t = 0; t < 2; ++t) {
    // ---- A-frags of A^T (L2-hot) ----
    v8s a1[3][2];
    #pragma unroll
    for (int nt = 0; nt < 3; ++nt)
      #pragma unroll
      for (int ks = 0; ks < 2; ++ks)
        a1[nt][ks] = *(const v8s*)(A1pk + (((t*3 + nt)*2 + ks) << 9) + lane*8);

    // ---- U A-frags in registers: row n, k-dim f; U = s1 .* x ----
    v8s uf[3][2];
    #pragma unroll
    for (int nt = 0; nt < 3; ++nt) {
      const int n = nt*16 + l15;
      if (nt < 2 || l15 < 8) {          // n < 40 (row-n outputs >=40 discarded)
        const float* xp = xb + n*64;
        const float* sp = s1 + (t*NB + n)*64;
        #pragma unroll
        for (int ks = 0; ks < 2; ++ks) {
          const int f0 = ks*32 + q*8;
          const float4 xa = *(const float4*)(xp + f0);
          const float4 xc = *(const float4*)(xp + f0 + 4);
          const float4 sa = *(const float4*)(sp + f0);
          const float4 sc = *(const float4*)(sp + f0 + 4);
          v8u uu;
          uu.u[0] = pk2(xa.x*sa.x, xa.y*sa.y);
          uu.u[1] = pk2(xa.z*sa.z, xa.w*sa.w);
          uu.u[2] = pk2(xc.x*sc.x, xc.y*sc.y);
          uu.u[3] = pk2(xc.z*sc.z, xc.w*sc.w);
          uf[nt][ks] = uu.v;
        }
      } else {
        uf[nt][0] = (v8s){0,0,0,0,0,0,0,0};
        uf[nt][1] = (v8s){0,0,0,0,0,0,0,0};
      }
    }

    // ---- GEMM1: V = sNT .* (A^T x) -> LDS (the one true transpose) ----
    #pragma unroll
    for (int nt = 0; nt < 3; ++nt) {
      #pragma unroll
      for (int dt = 0; dt < 4; ++dt) {
        v4f acc = {0.f, 0.f, 0.f, 0.f};
        acc = __builtin_amdgcn_mfma_f32_16x16x32_bf16(a1[nt][0], b1[dt][0], acc, 0, 0, 0);
        acc = __builtin_amdgcn_mfma_f32_16x16x32_bf16(a1[nt][1], b1[dt][1], acc, 0, 0, 0);
        const int d = dt*16 + l15;
        const float4 sv = *(const float4*)(sNT + (t*64 + d)*40 + nt*16 + q*4);
        #pragma unroll
        for (int r = 0; r < 4; ++r) {
          const int n = nt*16 + q*4 + r;
          if (n < NB) Vw[n*72 + d] = f2b(acc[r]*sv[r]);
        }
      }
    }

    // ---- V A-frags from LDS (same-wave RAW, lgkmcnt-ordered) ----
    v8s af[3][2];
    #pragma unroll
    for (int nt = 0; nt < 3; ++nt) {
      const unsigned short* rowV = Vw + (nt*16 + l15)*72;
      af[nt][0] = *(const v8s*)(rowV + q*8);
      af[nt][1] = *(const v8s*)(rowV + 32 + q*8);
    }

    // ---- GEMM2: h' = U*W2a + V*W2b + bias -> hLg (d-major, uint2) ----
    unsigned short* hLb = hLg + ((size_t)b*2 + t)*2560;
    #pragma unroll
    for (int dt = 0; dt < 4; ++dt) {
      v4f a2[3] = {{0,0,0,0},{0,0,0,0},{0,0,0,0}};
      #pragma unroll
      for (int ks = 0; ks < 4; ++ks) {
        const v8s w2k = *(const v8s*)(W2pk + ((t*16 + ks*4 + dt) << 9) + lane*8);
        const v8s aop0 = (ks == 0) ? uf[0][ks] : (ks == 1) ? uf[0][1] : af[0][ks-2];
        const v8s aop1 = (ks == 0) ? uf[1][ks] : (ks == 1) ? uf[1][1] : af[1][ks-2];
        const v8s aop2 = (ks == 0) ? uf[2][ks] : (ks == 1) ? uf[2][1] : af[2][ks-2];
        a2[0] = __builtin_amdgcn_mfma_f32_16x16x32_bf16(aop0, w2k, a2[0], 0, 0, 0);
        a2[1] = __builtin_amdgcn_mfma_f32_16x16x32_bf16(aop1, w2k, a2[1], 0, 0, 0);
        a2[2] = __builtin_amdgcn_mfma_f32_16x16x32_bf16(aop2, w2k, a2[2], 0, 0, 0);
      }
      const int d = dt*16 + l15;
      #pragma unroll
      for (int nt = 0; nt < 3; ++nt) {
        const int n0 = nt*16 + q*4;
        if (n0 < NB) {
          const float4 bv = *(const float4*)(bias2T + (t*64 + d)*40 + n0);
          uint2 pr;
          pr.x = pk2(a2[nt][0] + bv.x, a2[nt][1] + bv.y);
          pr.y = pk2(a2[nt][2] + bv.z, a2[nt][3] + bv.w);
          *(uint2*)(hLb + d*40 + n0) = pr;
        }
      }
    }
  }
}

// kernelB: 16 batches/block, 8 waves. GEMM3 (all 16 B-cols valid, Gpk once per
// block), depth-2 prefetch on the kt loop (loads are L3-latency ~400cyc),
// block softmax, vectorized pool.
__global__ __launch_bounds__(512) void kernelB(
    const unsigned short* __restrict__ hLg, const unsigned short* __restrict__ Gpk,
    const float* __restrict__ gate_b, float* __restrict__ out)
{
  __shared__ float pj[8 * 48 * 17];   // (w*48 + j)*17 + b
  __shared__ float wgt[2 * 16 * NB];  // [t][b][n]

  const int tid = threadIdx.x;
  const int w = tid >> 6, lane = tid & 63;
  const int l = lane & 15, q = lane >> 4;
  const int b0 = blockIdx.x * 16;

  v4f ac[2][3];
  #pragma unroll
  for (int t = 0; t < 2; ++t)
    #pragma unroll
    for (int jt = 0; jt < 3; ++jt)
      ac[t][jt] = (v4f){0.f, 0.f, 0.f, 0.f};

  const unsigned short* hb = hLg + (size_t)(b0 + l) * 2 * 2560 + q * 8;
  v8s g0[2], g1[2], g2[2], bf0[2], bf1[2];
  #pragma unroll
  for (int s = 0; s < 2; ++s) {
    const int kt = w + s*8;
    g0[s]  = *(const v8s*)(Gpk + ((kt*3+0) << 9) + lane*8);
    g1[s]  = *(const v8s*)(Gpk + ((kt*3+1) << 9) + lane*8);
    g2[s]  = *(const v8s*)(Gpk + ((kt*3+2) << 9) + lane*8);
    bf0[s] = *(const v8s*)(hb + kt*32);
    bf1[s] = *(const v8s*)(hb + 2560 + kt*32);
  }
  #pragma unroll
  for (int i = 0; i < 10; ++i) {
    const int cur = i & 1;
    const v8s G0 = g0[cur], G1 = g1[cur], G2 = g2[cur];
    const v8s B0 = bf0[cur], B1 = bf1[cur];
    if (i < 8) {
      const int ktn = w + (i+2)*8;
      g0[cur]  = *(const v8s*)(Gpk + ((ktn*3+0) << 9) + lane*8);
      g1[cur]  = *(const v8s*)(Gpk + ((ktn*3+1) << 9) + lane*8);
      g2[cur]  = *(const v8s*)(Gpk + ((ktn*3+2) << 9) + lane*8);
      bf0[cur] = *(const v8s*)(hb + ktn*32);
      bf1[cur] = *(const v8s*)(hb + 2560 + ktn*32);
    }
    ac[0][0] = __builtin_amdgcn_mfma_f32_16x16x32_bf16(G0, B0, ac[0][0], 0, 0, 0);
    ac[0][1] = __builtin_amdgcn_mfma_f32_16x16x32_bf16(G1, B0, ac[0][1], 0, 0, 0);
    ac[0][2] = __builtin_amdgcn_mfma_f32_16x16x32_bf16(G2, B0, ac[0][2], 0, 0, 0);
    ac[1][0] = __builtin_amdgcn_mfma_f32_16x16x32_bf16(G0, B1, ac[1][0], 0, 0, 0);
    ac[1][1] = __builtin_amdgcn_mfma_f32_16x16x32_bf16(G1, B1, ac[1][1], 0, 0, 0);
    ac[1][2] = __builtin_amdgcn_mfma_f32_16x16x32_bf16(G2, B1, ac[1][2], 0, 0, 0);
  }

  #pragma unroll
  for (int t = 0; t < 2; ++t) {
    if (t) __syncthreads();   // pj reuse: t=0 softmax reads done first
    #pragma unroll
    for (int jt = 0; jt < 3; ++jt)
      #pragma unroll
      for (int r = 0; r < 4; ++r)
        pj[(w*48 + jt*16 + q*4 + r)*17 + l] = ac[t][jt][r];
    __syncthreads();
    // softmax: wave w handles batches w*2, w*2+1; lane = j
    #pragma unroll
    for (int hb2 = 0; hb2 < 2; ++hb2) {
      const int bb = w*2 + hb2;
      float v = -3.0e38f;
      if (lane < NB) {
        v = gate_b[lane];
        #pragma unroll
        for (int w8 = 0; w8 < 8; ++w8) v += pj[(w8*48 + lane)*17 + bb];
      }
      float mx = v;
      #pragma unroll
      for (int m = 1; m < 64; m <<= 1) mx = fmaxf(mx, __shfl_xor(mx, m));
      const float e = (lane < NB) ? __expf(v - mx) : 0.f;
      float es = e;
      #pragma unroll
      for (int m = 1; m < 64; m <<= 1) es += __shfl_xor(es, m);
      if (lane < NB) wgt[(t*16 + bb)*NB + lane] = e / es;
    }
  }
  __syncthreads();
  // ---- pool: thread = (b, t, d-quad); 160 contiguous shorts = 20 uint4 ----
  {
    const int bb = tid >> 5, t = (tid >> 4) & 1, d0 = (tid & 15) * 4;
    const uint4* hp4 = (const uint4*)(hLg + ((size_t)(b0 + bb)*2 + t)*2560 + d0*40);
    const float* wb = wgt + (t*16 + bb)*NB;
    float s[4] = {0.f, 0.f, 0.f, 0.f};
    #pragma unroll
    for (int k = 0; k < 20; ++k) {
      const uint4 rr = hp4[k];
      const int e0 = k*8;
      s[(e0+0)/40] += blo(rr.x)*wb[(e0+0)%40]; s[(e0+1)/40] += bhi(rr.x)*wb[(e0+1)%40];
      s[(e0+2)/40] += blo(rr.y)*wb[(e0+2)%40]; s[(e0+3)/40] += bhi(rr.y)*wb[(e0+3)%40];
      s[(e0+4)/40] += blo(rr.z)*wb[(e0+4)%40]; s[(e0+5)/40] += bhi(rr.z)*wb[(e0+5)%40];
      s[(e0+6)/40] += blo(rr.w)*wb[(e0+6)%40]; s[(e0+7)/40] += bhi(rr.w)*wb[(e0+7)%40];
    }
    float4 ov = make_float4(s[0], s[1], s[2], s[3]);
    *(float4*)(out + ((size_t)(b0 + bb)*2 + t)*64 + d0) = ov;
  }
}

extern "C" void kernel_launch(void* const* d_in, const int* in_sizes, int n_in,
                              void* d_out, int out_size, void* d_ws, size_t ws_size,
                              hipStream_t stream) {
  const float* x        = (const float*)d_in[0];
  const float* masker   = (const float*)d_in[1];
  const float* ln_gamma = (const float*)d_in[2];
  const float* ln_beta  = (const float*)d_in[3];
  const float* gnn_w    = (const float*)d_in[4];
  const float* gnn_b    = (const float*)d_in[5];
  const float* bn_gamma = (const float*)d_in[6];
  const float* bn_beta  = (const float*)d_in[7];
  const float* bn_mean  = (const float*)d_in[8];
  const float* bn_var   = (const float*)d_in[9];
  const float* gate_w   = (const float*)d_in[10];
  const float* gate_b   = (const float*)d_in[11];
  float* out = (float*)d_out;

  char* ws = (char*)d_ws;
  unsigned short* A1pk   = (unsigned short*)(ws + 0);
  unsigned short* W2pk   = (unsigned short*)(ws + 12288);
  unsigned short* Gpk    = (unsigned short*)(ws + 45056);
  float*          s1     = (float*)(ws + 290816);
  float*          sNT    = (float*)(ws + 311296);
  float*          bias2T = (float*)(ws + 331904);
  unsigned short* hLg    = (unsigned short*)(ws + 352512);

  prep<<<64, 256, 0, stream>>>(masker, ln_gamma, ln_beta, gnn_w, gnn_b,
                               bn_gamma, bn_beta, bn_mean, bn_var, gate_w,
                               A1pk, W2pk, Gpk, s1, sNT, bias2T);
  kernelA<<<2048, 256, 0, stream>>>(x, A1pk, W2pk, s1, sNT, bias2T, hLg);
  kernelB<<<512, 512, 0, stream>>>(hLg, Gpk, gate_b, out);
}

// Round 6
// 238.371 us; speedup vs baseline: 1.1644x; 1.1644x over previous
//
#include <hip/hip_runtime.h>
#include <hip/hip_bf16.h>
#include <stdint.h>

typedef float v4f __attribute__((ext_vector_type(4)));
typedef short v8s __attribute__((ext_vector_type(8)));

#define NB 40

__device__ __forceinline__ unsigned short f2b(float f) {
  __hip_bfloat16 h = __float2bfloat16(f);
  unsigned short u;
  __builtin_memcpy(&u, &h, 2);
  return u;
}
__device__ __forceinline__ unsigned pk2(float lo, float hi) {
  __hip_bfloat162 h = __float22bfloat162_rn(make_float2(lo, hi));
  unsigned u;
  __builtin_memcpy(&u, &h, 4);
  return u;
}
__device__ __forceinline__ float b2f16(unsigned short h) {
  return __uint_as_float(((unsigned)h) << 16);
}
__device__ __forceinline__ float blo(unsigned u) { return __uint_as_float(u << 16); }
__device__ __forceinline__ float bhi(unsigned u) { return __uint_as_float(u & 0xFFFF0000u); }

// ws layout (bytes):
//  A1pk   @ 0        : 12288     (2t x 3nt x 2ks A^T A-frags, zero n>=40 / m>=40)
//  W2pk   @ 12288    : 32768     (2t x 4ks x 4dt B-frags of gnn_w)
//  Gpk    @ 45056    : 245760    (80kt x 3jt A-frags of gate_w^T, K n-major fl=n*64+d)
//  s1     @ 290816   : 20480     s for f<64, [t][n][d] f32
//  sNT    @ 311296   : 20480+128 s for f>=64, [t][d][n] f32 (+pad)
//  bias2T @ 331904   : 20480     gnn_b + all-BN-offset fold, [t][d][n] f32

// prep: params only. block 0: adjacency -> LN -> softmax -> A1pk (wave-parallel).
// blocks 1..63: everything else.
__global__ __launch_bounds__(256) void prep(
    const float* __restrict__ masker,
    const float* __restrict__ ln_gamma, const float* __restrict__ ln_beta,
    const float* __restrict__ gnn_w, const float* __restrict__ gnn_b,
    const float* __restrict__ bn_gamma, const float* __restrict__ bn_beta,
    const float* __restrict__ bn_mean, const float* __restrict__ bn_var,
    const float* __restrict__ gate_w,
    unsigned short* __restrict__ A1pk, unsigned short* __restrict__ W2pk,
    unsigned short* __restrict__ Gpk, float* __restrict__ s1,
    float* __restrict__ sNT, float* __restrict__ bias2T)
{
  const int tid = threadIdx.x;
  if (blockIdx.x == 0) {
    __shared__ float AtL[2 * NB * NB];
    const int w = tid >> 6, lane = tid & 63;
    #pragma unroll 1
    for (int it = 0; it < 20; ++it) {
      const int c = it * 4 + w;        // 0..79
      const int t = c / NB, n = c % NB;
      const int m = lane;              // valid < 40
      float adj = 0.f;
      if (m < NB) {
        float p = masker[((t*3+0)*NB+m)*NB+n]
                * masker[((t*3+1)*NB+m)*NB+n]
                * masker[((t*3+2)*NB+m)*NB+n];
        adj = p > 0.f ? p : 0.f;
      }
      float s = adj;
      #pragma unroll
      for (int d = 1; d < 64; d <<= 1) s += __shfl_xor(s, d);
      const float mu = s * (1.f/NB);
      const float dv = (m < NB) ? adj - mu : 0.f;
      float v2 = dv * dv;
      #pragma unroll
      for (int d = 1; d < 64; d <<= 1) v2 += __shfl_xor(v2, d);
      const float inv = rsqrtf(v2 * (1.f/NB) + 1e-5f);
      float val = -3.0e38f;
      if (m < NB) {
        float lnv = dv * inv * ln_gamma[m] + ln_beta[m];
        val = lnv + (adj != 0.f ? 0.f : -1e9f) + (m == n ? 1.f : 0.f);
      }
      float mx = val;
      #pragma unroll
      for (int d = 1; d < 64; d <<= 1) mx = fmaxf(mx, __shfl_xor(mx, d));
      const float e = (m < NB) ? __expf(val - mx) : 0.f;
      float es = e;
      #pragma unroll
      for (int d = 1; d < 64; d <<= 1) es += __shfl_xor(es, d);
      if (m < NB)
        AtL[(t*NB+n)*NB + m] = (adj != 0.f) ? e / es : 0.f;
    }
    __syncthreads();
    for (int e = tid; e < 6144; e += 256) {
      int frag = e >> 9, rem = e & 511, lane2 = rem >> 3, jj = rem & 7;
      int t = frag / 6, r2 = frag % 6, nt = r2 >> 1, ks = r2 & 1;
      int n = nt*16 + (lane2 & 15);
      int m = ks*32 + (lane2 >> 4)*8 + jj;
      A1pk[e] = f2b((n < NB && m < NB) ? AtL[(t*NB+n)*NB+m] : 0.f);
    }
  } else {
    const int gid = (blockIdx.x - 1) * 256 + tid, gsz = 63 * 256;
    for (int e = gid; e < 16384; e += gsz) {
      int frag = e >> 9, rem = e & 511, lane = rem >> 3, jj = rem & 7;
      int t = frag >> 4, ks = (frag >> 2) & 3, dt = frag & 3;
      int f = ks*32 + (lane >> 4)*8 + jj, d = dt*16 + (lane & 15);
      W2pk[e] = f2b(gnn_w[t*8192 + f*64 + d]);
    }
    // Gpk: K n-major (fl = n*64+d flat index), matches hL layout in kernelM
    for (int e = gid; e < 122880; e += gsz) {
      int frag = e >> 9, rem = e & 511, lane = rem >> 3, jj = rem & 7;
      int kt = frag / 3, jt = frag % 3;
      int fl = kt*32 + (lane >> 4)*8 + jj, j = jt*16 + (lane & 15);
      Gpk[e] = f2b(j < NB ? gate_w[fl*NB + j] : 0.f);
    }
    for (int e = gid; e < 5120; e += gsz) {
      int t = e / 2560, n = (e % 2560) / 64, d = e & 63;
      int F = (t*NB + n)*128 + d;
      s1[e] = bn_gamma[F] * rsqrtf(bn_var[F] + 1e-5f);
    }
    for (int e = gid; e < 5120; e += gsz) {
      int t = e / 2560, d = (e % 2560) / 40, n = e % 40;
      int F = (t*NB + n)*128 + 64 + d;
      sNT[e] = bn_gamma[F] * rsqrtf(bn_var[F] + 1e-5f);
    }
    for (int e4 = gid; e4 < 20480; e4 += gsz) {
      int e = e4 >> 2, part = e4 & 3;
      int t = e / 2560, d = (e % 2560) / 40, n = e % 40;
      float acc = (part == 0) ? gnn_b[(t*NB + n)*64 + d] : 0.f;
      int Fb = (t*NB + n)*128;
      int f0 = part * 32;
      for (int f = f0; f < f0 + 32; ++f) {
        float s = bn_gamma[Fb+f] * rsqrtf(bn_var[Fb+f] + 1e-5f);
        float o = bn_beta[Fb+f] - bn_mean[Fb+f] * s;
        acc += o * gnn_w[t*8192 + f*64 + d];
      }
      acc += __shfl_xor(acc, 1);
      acc += __shfl_xor(acc, 2);
      if (part == 0) bias2T[e] = acc;
    }
  }
}

// kernelM: t-split fused kernel. Each block = (t = bid&1, 4 batches), running
// the r2-verified single-t pipeline: x load -> x^T stage -> phaseA(U) -> GEMM1
// -> GEMM2 -> hL -> GEMM3(+depth-2 Gpk prefetch) -> softmax -> pool -> out.
// Half the serial chain of the t-looped version, 2x the block count.
__global__ __launch_bounds__(256) void kernelM(
    const float* __restrict__ x,
    const unsigned short* __restrict__ A1pk, const unsigned short* __restrict__ W2pk,
    const unsigned short* __restrict__ Gpk, const float* __restrict__ s1,
    const float* __restrict__ sNT, const float* __restrict__ bias2T,
    const float* __restrict__ gate_b, float* __restrict__ out)
{
  __shared__ __align__(16) unsigned short hc[160 * 136];  // 43520 B (xT stage + U|V + hL)
  __shared__ float pj[16 * 48];                           // [w*4+b][j]

  const int tid = threadIdx.x;
  const int lane = tid & 63;
  const int w = tid >> 6;
  const int l = lane & 15, q = lane >> 4;
  const int t = blockIdx.x & 1;
  const int b0 = (blockIdx.x >> 1) * 4;
  unsigned* hcU = (unsigned*)hc;
  unsigned short* hL = hc;   // alias: hL (4*2568 shorts) lives inside hc after GEMM2

  // ---- load x f32 -> packed bf16 regs; stage x^T bf16 in hc for b1 frags ----
  uint4 xr[5];
  #pragma unroll
  for (int it = 0; it < 5; ++it) {
    const int c = it * 256 + tid, row = c >> 3, dp8 = c & 7;
    const float* xp = x + (size_t)b0 * 2560 + row * 64 + dp8 * 8;
    const float4 f0 = *(const float4*)xp;
    const float4 f1 = *(const float4*)(xp + 4);
    xr[it] = make_uint4(pk2(f0.x, f0.y), pk2(f0.z, f0.w),
                        pk2(f1.x, f1.y), pk2(f1.z, f1.w));
  }
  if (tid < 12) hcU[5120 + tid] = 0u;   // zero 24-short tail: b1 k-overrun stays finite
  #pragma unroll
  for (int it = 0; it < 5; ++it) {
    const int c = it * 256 + tid, row = c >> 3, dp8 = c & 7;
    const int bq = row / NB, n = row - bq * NB;
    unsigned short* base = hc + (bq * 64 + dp8 * 8) * NB + n;
    const unsigned uu0 = xr[it].x, uu1 = xr[it].y, uu2 = xr[it].z, uu3 = xr[it].w;
    base[0*NB] = (unsigned short)(uu0 & 0xFFFF);
    base[1*NB] = (unsigned short)(uu0 >> 16);
    base[2*NB] = (unsigned short)(uu1 & 0xFFFF);
    base[3*NB] = (unsigned short)(uu1 >> 16);
    base[4*NB] = (unsigned short)(uu2 & 0xFFFF);
    base[5*NB] = (unsigned short)(uu2 >> 16);
    base[6*NB] = (unsigned short)(uu3 & 0xFFFF);
    base[7*NB] = (unsigned short)(uu3 >> 16);
  }
  __syncthreads();
  v8s b1[4][2];
  #pragma unroll
  for (int i = 0; i < 4; ++i)
    #pragma unroll
    for (int ks = 0; ks < 2; ++ks)
      b1[i][ks] = *(const v8s*)(hc + ((w * 4 + i) * 16 + l) * NB + ks * 32 + q * 8);
  __syncthreads();

  // per-t fragments
  v8s a1[3][2], w2[4];
  #pragma unroll
  for (int nt = 0; nt < 3; ++nt)
    #pragma unroll
    for (int ks = 0; ks < 2; ++ks)
      a1[nt][ks] = *(const v8s*)(A1pk + (((t*3 + nt)*2 + ks) << 9) + lane*8);
  #pragma unroll
  for (int ks = 0; ks < 4; ++ks)
    w2[ks] = *(const v8s*)(W2pk + (((t*4 + ks)*4 + w) << 9) + lane*8);

  // ---- Phase A: hc x-half = s1 .* x (offsets folded into bias2T) ----
  #pragma unroll
  for (int it = 0; it < 5; ++it) {
    const int c = it*256 + tid;
    const int row = c >> 3, dp8 = c & 7;
    const uint4 xv = xr[it];
    const int n = row % NB;
    const float4 sA = *(const float4*)(s1 + (t*NB + n)*64 + dp8*8);
    const float4 sB = *(const float4*)(s1 + (t*NB + n)*64 + dp8*8 + 4);
    uint4 p;
    p.x = pk2(blo(xv.x)*sA.x, bhi(xv.x)*sA.y);
    p.y = pk2(blo(xv.y)*sA.z, bhi(xv.y)*sA.w);
    p.z = pk2(blo(xv.z)*sB.x, bhi(xv.z)*sB.y);
    p.w = pk2(blo(xv.w)*sB.z, bhi(xv.w)*sB.w);
    *(uint4*)(hcU + row*68 + dp8*4) = p;
  }
  // ---- GEMM1 + scale -> hc nei-half ----
  #pragma unroll
  for (int i = 0; i < 4; ++i) {
    const int R = (w*4+i)*16 + l;
    const int bb = R >> 6, d = R & 63;
    #pragma unroll
    for (int nt = 0; nt < 3; ++nt) {
      v4f acc = {0.f, 0.f, 0.f, 0.f};
      acc = __builtin_amdgcn_mfma_f32_16x16x32_bf16(a1[nt][0], b1[i][0], acc, 0, 0, 0);
      acc = __builtin_amdgcn_mfma_f32_16x16x32_bf16(a1[nt][1], b1[i][1], acc, 0, 0, 0);
      const float4 sv = *(const float4*)(sNT + (t*64+d)*40 + nt*16 + q*4);
      #pragma unroll
      for (int r = 0; r < 4; ++r) {
        int n = nt*16 + q*4 + r;
        if (n < NB) hc[(bb*NB + n)*136 + 64 + d] = f2b(acc[r]*sv[r]);
      }
    }
  }
  __syncthreads();
  // ---- GEMM2 + bias2T -> packed regs (hL aliases hc, so write after barrier) ----
  unsigned pkr0[10], pkr1[10];
  #pragma unroll
  for (int mt = 0; mt < 10; ++mt) {
    v4f acc = {0.f, 0.f, 0.f, 0.f};
    #pragma unroll
    for (int ks = 0; ks < 4; ++ks) {
      v8s af = *(const v8s*)(hc + (mt*16 + l)*136 + ks*32 + q*8);
      acc = __builtin_amdgcn_mfma_f32_16x16x32_bf16(af, w2[ks], acc, 0, 0, 0);
    }
    const int d = w*16 + l;
    const int G = mt*16 + q*4;
    const int bb = G / NB, n0 = G - bb*NB;
    const float4 bv = *(const float4*)(bias2T + (t*64+d)*40 + n0);
    pkr0[mt] = pk2(acc[0] + bv.x, acc[1] + bv.y);
    pkr1[mt] = pk2(acc[2] + bv.z, acc[3] + bv.w);
  }
  __syncthreads();
  #pragma unroll
  for (int mt = 0; mt < 10; ++mt) {
    const int d = w*16 + l;
    const int G = mt*16 + q*4;
    const int bb = G / NB, n0 = G - bb*NB;
    hL[bb*2568 + (n0+0)*64 + d] = (unsigned short)(pkr0[mt] & 0xFFFF);
    hL[bb*2568 + (n0+1)*64 + d] = (unsigned short)(pkr0[mt] >> 16);
    hL[bb*2568 + (n0+2)*64 + d] = (unsigned short)(pkr1[mt] & 0xFFFF);
    hL[bb*2568 + (n0+3)*64 + d] = (unsigned short)(pkr1[mt] >> 16);
  }
  __syncthreads();
  // ---- GEMM3: logits (A=Gpk rows j, B=hL cols b); depth-2 Gpk prefetch ----
  v4f ac0 = {0,0,0,0}, ac1 = {0,0,0,0}, ac2 = {0,0,0,0};
  {
    v8s pg0[2], pg1[2], pg2[2], pbf[2];
    #pragma unroll
    for (int s = 0; s < 2; ++s) {
      const int kt = w + s*4;
      pg0[s] = *(const v8s*)(Gpk + ((kt*3+0) << 9) + lane*8);
      pg1[s] = *(const v8s*)(Gpk + ((kt*3+1) << 9) + lane*8);
      pg2[s] = *(const v8s*)(Gpk + ((kt*3+2) << 9) + lane*8);
      pbf[s] = *(const v8s*)(hL + (l & 3)*2568 + kt*32 + q*8);
    }
    #pragma unroll
    for (int i = 0; i < 20; ++i) {
      const int cur = i & 1;
      const v8s G0 = pg0[cur], G1 = pg1[cur], G2 = pg2[cur], BF = pbf[cur];
      if (i < 18) {
        const int ktn = w + (i+2)*4;
        pg0[cur] = *(const v8s*)(Gpk + ((ktn*3+0) << 9) + lane*8);
        pg1[cur] = *(const v8s*)(Gpk + ((ktn*3+1) << 9) + lane*8);
        pg2[cur] = *(const v8s*)(Gpk + ((ktn*3+2) << 9) + lane*8);
        pbf[cur] = *(const v8s*)(hL + (l & 3)*2568 + ktn*32 + q*8);
      }
      ac0 = __builtin_amdgcn_mfma_f32_16x16x32_bf16(G0, BF, ac0, 0, 0, 0);
      ac1 = __builtin_amdgcn_mfma_f32_16x16x32_bf16(G1, BF, ac1, 0, 0, 0);
      ac2 = __builtin_amdgcn_mfma_f32_16x16x32_bf16(G2, BF, ac2, 0, 0, 0);
    }
  }
  if (l < 4) {
    #pragma unroll
    for (int r = 0; r < 4; ++r) {
      pj[(w*4 + l)*48 +  0 + q*4 + r] = ac0[r];
      pj[(w*4 + l)*48 + 16 + q*4 + r] = ac1[r];
      pj[(w*4 + l)*48 + 32 + q*4 + r] = ac2[r];
    }
  }
  __syncthreads();
  // ---- per-wave softmax (batch = w) + pool ----
  {
    float v = -3.0e38f;
    if (lane < NB) {
      v = gate_b[lane];
      #pragma unroll
      for (int ww = 0; ww < 4; ++ww) v += pj[(ww*4 + w)*48 + lane];
    }
    float mx = v;
    #pragma unroll
    for (int m = 1; m < 64; m <<= 1) mx = fmaxf(mx, __shfl_xor(mx, m));
    float e = (lane < NB) ? __expf(v - mx) : 0.f;
    float es = e;
    #pragma unroll
    for (int m = 1; m < 64; m <<= 1) es += __shfl_xor(es, m);
    const float wgt = e / es;   // lane's weight for field n=lane
    float accp = 0.f;
    #pragma unroll 8
    for (int n = 0; n < NB; ++n)
      accp += b2f16(hL[w*2568 + n*64 + lane]) * __shfl(wgt, n);
    out[((size_t)(b0 + w)*2 + t)*64 + lane] = accp;
  }
}

extern "C" void kernel_launch(void* const* d_in, const int* in_sizes, int n_in,
                              void* d_out, int out_size, void* d_ws, size_t ws_size,
                              hipStream_t stream) {
  const float* x        = (const float*)d_in[0];
  const float* masker   = (const float*)d_in[1];
  const float* ln_gamma = (const float*)d_in[2];
  const float* ln_beta  = (const float*)d_in[3];
  const float* gnn_w    = (const float*)d_in[4];
  const float* gnn_b    = (const float*)d_in[5];
  const float* bn_gamma = (const float*)d_in[6];
  const float* bn_beta  = (const float*)d_in[7];
  const float* bn_mean  = (const float*)d_in[8];
  const float* bn_var   = (const float*)d_in[9];
  const float* gate_w   = (const float*)d_in[10];
  const float* gate_b   = (const float*)d_in[11];
  float* out = (float*)d_out;

  char* ws = (char*)d_ws;
  unsigned short* A1pk   = (unsigned short*)(ws + 0);
  unsigned short* W2pk   = (unsigned short*)(ws + 12288);
  unsigned short* Gpk    = (unsigned short*)(ws + 45056);
  float*          s1     = (float*)(ws + 290816);
  float*          sNT    = (float*)(ws + 311296);
  float*          bias2T = (float*)(ws + 331904);

  prep<<<64, 256, 0, stream>>>(masker, ln_gamma, ln_beta, gnn_w, gnn_b,
                               bn_gamma, bn_beta, bn_mean, bn_var, gate_w,
                               A1pk, W2pk, Gpk, s1, sNT, bias2T);
  kernelM<<<4096, 256, 0, stream>>>(x, A1pk, W2pk, Gpk,
                                    s1, sNT, bias2T, gate_b, out);
}